// Round 16
// baseline (232.245 us; speedup 1.0000x reference)
//
#include <hip/hip_runtime.h>
#include <hip/hip_bf16.h>

#define N_NODES 100000
#define N_EDGES 1600000
#define N_GRAPHS 512
#define NODE_DIM 64
#define GRAPH_DIM 16
#define HIDDEN 128
#define OUT_DIM 8

#define NBUCKETS 391      // ceil(N_NODES/256)
#define BIN_CAP 8192      // per-bucket bin + csr capacity (avg 4092)
#define EPB 4096          // edges per binning block
#define NB_BIN 391        // binplace blocks = ceil(N_EDGES/EPB)
#define NB_PACK 1563      // packstat blocks = ceil(N_NODES/64)

__device__ __forceinline__ float bflo(unsigned u) { return __uint_as_float(u << 16); }
__device__ __forceinline__ float bfhi(unsigned u) { return __uint_as_float(u & 0xffff0000u); }

// ---- merged phase A: blocks [0,NB_BIN) bin edges by dst>>8; blocks [NB_BIN,..) pack x + graph stats ----

__global__ __launch_bounds__(256) void k_binpack(const int* __restrict__ src,
                                                 const int* __restrict__ dst,
                                                 int* __restrict__ gcur,
                                                 unsigned* __restrict__ bin,
                                                 const float* __restrict__ x,
                                                 const int* __restrict__ batch,
                                                 ushort* __restrict__ xb,
                                                 float* __restrict__ gt_sum) {
    int t = threadIdx.x;
    if (blockIdx.x < NB_BIN) {
        __shared__ int cnt[NBUCKETS];
        __shared__ int base[NBUCKETS];
        for (int i = t; i < NBUCKETS; i += 256) cnt[i] = 0;
        __syncthreads();
        int e0 = blockIdx.x * EPB;
#pragma unroll
        for (int k = 0; k < EPB / 256; k++) {
            int e = e0 + k * 256 + t;
            if (e < N_EDGES) atomicAdd(&cnt[dst[e] >> 8], 1);
        }
        __syncthreads();
        for (int i = t; i < NBUCKETS; i += 256) {
            int c = cnt[i];
            base[i] = (c > 0) ? atomicAdd(&gcur[i], c) : 0;
            cnt[i] = 0;
        }
        __syncthreads();
#pragma unroll
        for (int k = 0; k < EPB / 256; k++) {
            int e = e0 + k * 256 + t;
            if (e < N_EDGES) {
                int d = dst[e];
                int b = d >> 8;
                int p = atomicAdd(&cnt[b], 1);
                bin[(size_t)b * BIN_CAP + base[b] + p] = ((unsigned)src[e] << 8) | (unsigned)(d & 255);
            }
        }
    } else {
        int i0 = (blockIdx.x - NB_BIN) * 64;
        for (int idx = t; idx < 64 * 32; idx += 256) {
            int node = i0 + (idx >> 5);
            if (node < N_NODES) {
                int c2 = idx & 31;
                float2 v = *(const float2*)&x[(size_t)node * 80 + c2 * 2];
                __hip_bfloat16 lo = __float2bfloat16(v.x);
                __hip_bfloat16 hi = __float2bfloat16(v.y);
                ushort2 pv = make_ushort2(*(ushort*)&lo, *(ushort*)&hi);
                ((ushort2*)xb)[(size_t)node * 32 + c2] = pv;
            }
        }
        int c = t & 15, sub = t >> 4;  // 16 subs x 16 channels
        int iend = min(i0 + 64, N_NODES);
        float acc = 0.0f;
        int g = -1;
        for (int i = i0 + sub; i < iend; i += 16) {
            int bi = batch[i];
            if (bi != g) {
                if (g >= 0) atomicAdd(&gt_sum[g * GRAPH_DIM + c], acc);
                acc = 0.0f; g = bi;
            }
            acc += x[(size_t)i * 80 + NODE_DIM + c];
        }
        if (g >= 0) atomicAdd(&gt_sum[g * GRAPH_DIM + c], acc);
    }
}

// ---- phase B (fused): count -> dinv + rowse -> CSR fill -> in-place rescale xb *= dinv ----

__global__ __launch_bounds__(256) void k_build(const int* __restrict__ gcur,
                                               const unsigned* __restrict__ bin,
                                               float* __restrict__ dinv,
                                               int2* __restrict__ rowse,
                                               int* __restrict__ csr,
                                               ushort* __restrict__ xb) {
    __shared__ int cnt[256];
    __shared__ int sc[256];
    __shared__ int rsl[256];
    __shared__ float dl[256];
    int b = blockIdx.x, t = threadIdx.x;
    cnt[t] = 0;
    __syncthreads();
    int n = gcur[b];
    const unsigned* seg = bin + (size_t)b * BIN_CAP;
    for (int i = t; i < n; i += 256) atomicAdd(&cnt[seg[i] & 255u], 1);
    __syncthreads();
    int deg = cnt[t];
    sc[t] = deg;
    __syncthreads();
    for (int o = 1; o < 256; o <<= 1) {
        int u = (t >= o) ? sc[t - o] : 0;
        __syncthreads();
        sc[t] += u;
        __syncthreads();
    }
    int rs = b * BIN_CAP + sc[t] - deg;   // bucket-region base, exclusive prefix
    int node = b * 256 + t;
    float dv = rsqrtf((float)deg + 1.0f);
    if (node < N_NODES) {
        dinv[node] = dv;
        rowse[node] = make_int2(rs, rs + deg);
    }
    rsl[t] = rs;
    dl[t] = dv;
    cnt[t] = 0;
    __syncthreads();
    for (int i = t; i < n; i += 256) {
        unsigned e = seg[i];
        int dlidx = (int)(e & 255u);
        csr[rsl[dlidx] + atomicAdd(&cnt[dlidx], 1)] = (int)(e >> 8);
    }
    __syncthreads();
    // in-place rescale: xs = bf16(dinv * xb)
    unsigned* xw = (unsigned*)xb;
    for (int idx = t; idx < 256 * 32; idx += 256) {
        int nl = idx >> 5;
        int nn = b * 256 + nl;
        if (nn < N_NODES) {
            int c2 = idx & 31;
            unsigned u = xw[(size_t)nn * 32 + c2];
            float d = dl[nl];
            float lo = bflo(u) * d;
            float hi = bfhi(u) * d;
            __hip_bfloat16 l2 = __float2bfloat16(lo);
            __hip_bfloat16 h2 = __float2bfloat16(hi);
            xw[(size_t)nn * 32 + c2] = ((unsigned)(*(ushort*)&h2) << 16) | (unsigned)(*(ushort*)&l2);
        }
    }
}

// ---- fused conv1: weightless unroll-8 cascade gather + full-block GEMM; zeroes gsum2 ----
// 512 threads = 8 waves = 16 nodes/block; GEMM: 16 rows, 4 outputs/thread.

#define LDX(s_) __uint_as_float((unsigned)xb[(size_t)(s_)*64 + lane] << 16)

#define C1_E8(kX, aX0, aX1, aX2, aX3) {                                              \
    int s0 = csr[kX],     s1 = csr[kX + 1], s2 = csr[kX + 2], s3 = csr[kX + 3];      \
    int s4 = csr[kX + 4], s5 = csr[kX + 5], s6 = csr[kX + 6], s7 = csr[kX + 7];      \
    float v0 = LDX(s0), v1 = LDX(s1), v2 = LDX(s2), v3 = LDX(s3);                    \
    float v4 = LDX(s4), v5 = LDX(s5), v6 = LDX(s6), v7 = LDX(s7);                    \
    aX0 += v0; aX1 += v1; aX2 += v2; aX3 += v3;                                      \
    aX0 += v4; aX1 += v5; aX2 += v6; aX3 += v7; }

#define C1_E4(kX, aX0, aX1, aX2, aX3) {                                              \
    int s0 = csr[kX], s1 = csr[kX + 1], s2 = csr[kX + 2], s3 = csr[kX + 3];          \
    float v0 = LDX(s0), v1 = LDX(s1), v2 = LDX(s2), v3 = LDX(s3);                    \
    aX0 += v0; aX1 += v1; aX2 += v2; aX3 += v3; }

#define C1_E1(kX, aX0) { int s0 = csr[kX]; aX0 += LDX(s0); }

__global__ __launch_bounds__(512) void k_conv1(const int* __restrict__ csr,
                                               const int2* __restrict__ rowse,
                                               const float* __restrict__ dinv,
                                               const ushort* __restrict__ xb,
                                               const float* __restrict__ W,
                                               const float* __restrict__ bias,
                                               ushort* __restrict__ C,
                                               float* __restrict__ gsum2) {
    __shared__ float zs[16][64];
    int t = threadIdx.x;
    if (blockIdx.x < 128) gsum2[blockIdx.x * 512 + t] = 0.0f;
    int w = t >> 6, lane = t & 63;
    int nA = blockIdx.x * 16 + w * 2;
    int nB = nA + 1;
    int2 seA = rowse[nA];
    int2 seB = rowse[nB];
    int kA = seA.x, reA = seA.y;
    int kB = seB.x, reB = seB.y;
    float dA = dinv[nA], dB = dinv[nB];
    float selfA = LDX(nA);     // hoisted self-term loads (issue early)
    float selfB = LDX(nB);
    float aA0 = 0.f, aA1 = 0.f, aA2 = 0.f, aA3 = 0.f;
    float aB0 = 0.f, aB1 = 0.f, aB2 = 0.f, aB3 = 0.f;
    while (kA + 8 <= reA && kB + 8 <= reB) {
        C1_E8(kA, aA0, aA1, aA2, aA3)
        C1_E8(kB, aB0, aB1, aB2, aB3)
        kA += 8; kB += 8;
    }
    while (kA + 8 <= reA) { C1_E8(kA, aA0, aA1, aA2, aA3) kA += 8; }
    while (kB + 8 <= reB) { C1_E8(kB, aB0, aB1, aB2, aB3) kB += 8; }
    while (kA + 4 <= reA && kB + 4 <= reB) {
        C1_E4(kA, aA0, aA1, aA2, aA3)
        C1_E4(kB, aB0, aB1, aB2, aB3)
        kA += 4; kB += 4;
    }
    while (kA + 4 <= reA) { C1_E4(kA, aA0, aA1, aA2, aA3) kA += 4; }
    while (kB + 4 <= reB) { C1_E4(kB, aB0, aB1, aB2, aB3) kB += 4; }
    while (kA < reA && kB < reB) { C1_E1(kA, aA0) C1_E1(kB, aB0) kA++; kB++; }
    while (kA < reA) { C1_E1(kA, aA0) kA++; }
    while (kB < reB) { C1_E1(kB, aB0) kB++; }
    zs[w * 2][lane]     = dA * (aA0 + aA1 + aA2 + aA3 + selfA);
    zs[w * 2 + 1][lane] = dB * (aB0 + aB1 + aB2 + aB3 + selfB);
    __syncthreads();
    // GEMM phase: all 512 threads; j = t&127, quarter q computes rows q*4 .. q*4+3
    {
        int j = t & 127;
        int q = t >> 7;  // 0..3
        float acc[4];
#pragma unroll
        for (int m = 0; m < 4; m++) acc[m] = 0.0f;
        for (int k = 0; k < 64; k++) {
            float wk = W[k * 128 + j];
#pragma unroll
            for (int m = 0; m < 4; m++) acc[m] += zs[q * 4 + m][k] * wk;
        }
        float b = bias[j];
        size_t row0 = (size_t)blockIdx.x * 16 + q * 4;
#pragma unroll
        for (int m = 0; m < 4; m++) {
            float v = fmaxf(acc[m] + b, 0.0f) * dinv[row0 + m];
            __hip_bfloat16 hv = __float2bfloat16(v);
            C[(row0 + m) * 128 + j] = *(ushort*)&hv;
        }
    }
}

// ---- gather2: weightless unroll-8 cascade (hs bf16, 512 thr = 16 nodes) + fused mean-pool ----

#define ADD2(acc_, u_) { acc_.x += bflo(u_); acc_.y += bfhi(u_); }

#define G2_E8(kX, aX0, aX1, aX2, aX3) {                                              \
    int s0 = csr[kX],     s1 = csr[kX + 1], s2 = csr[kX + 2], s3 = csr[kX + 3];      \
    int s4 = csr[kX + 4], s5 = csr[kX + 5], s6 = csr[kX + 6], s7 = csr[kX + 7];      \
    unsigned u0 = h[(size_t)s0 * 64 + lane], u1 = h[(size_t)s1 * 64 + lane];         \
    unsigned u2 = h[(size_t)s2 * 64 + lane], u3 = h[(size_t)s3 * 64 + lane];         \
    unsigned u4 = h[(size_t)s4 * 64 + lane], u5 = h[(size_t)s5 * 64 + lane];         \
    unsigned u6 = h[(size_t)s6 * 64 + lane], u7 = h[(size_t)s7 * 64 + lane];         \
    ADD2(aX0, u0) ADD2(aX1, u1) ADD2(aX2, u2) ADD2(aX3, u3)                          \
    ADD2(aX0, u4) ADD2(aX1, u5) ADD2(aX2, u6) ADD2(aX3, u7) }

#define G2_E4(kX, aX0, aX1, aX2, aX3) {                                              \
    int s0 = csr[kX], s1 = csr[kX + 1], s2 = csr[kX + 2], s3 = csr[kX + 3];          \
    unsigned u0 = h[(size_t)s0 * 64 + lane], u1 = h[(size_t)s1 * 64 + lane];         \
    unsigned u2 = h[(size_t)s2 * 64 + lane], u3 = h[(size_t)s3 * 64 + lane];         \
    ADD2(aX0, u0) ADD2(aX1, u1) ADD2(aX2, u2) ADD2(aX3, u3) }

#define G2_E1(kX, aX0) {                                                             \
    int s0 = csr[kX];                                                                \
    unsigned u0 = h[(size_t)s0 * 64 + lane];                                         \
    ADD2(aX0, u0) }

__global__ __launch_bounds__(512) void k_gather2(const int* __restrict__ csr,
                                                 const int2* __restrict__ rowse,
                                                 const float* __restrict__ dinv,
                                                 const unsigned* __restrict__ h,
                                                 const int* __restrict__ batch,
                                                 float* __restrict__ gsum2) {
    __shared__ float2 red[16][64];
    int t = threadIdx.x;
    int w = t >> 6, lane = t & 63;
    int nA = blockIdx.x * 16 + w * 2;
    int nB = nA + 1;
    int2 seA = rowse[nA];
    int2 seB = rowse[nB];
    int kA = seA.x, reA = seA.y;
    int kB = seB.x, reB = seB.y;
    float dA = dinv[nA], dB = dinv[nB];
    unsigned usA = h[(size_t)nA * 64 + lane];   // hoisted self-term loads
    unsigned usB = h[(size_t)nB * 64 + lane];
    float2 aA0 = {0.f,0.f}, aA1 = {0.f,0.f}, aA2 = {0.f,0.f}, aA3 = {0.f,0.f};
    float2 aB0 = {0.f,0.f}, aB1 = {0.f,0.f}, aB2 = {0.f,0.f}, aB3 = {0.f,0.f};
    while (kA + 8 <= reA && kB + 8 <= reB) {
        G2_E8(kA, aA0, aA1, aA2, aA3)
        G2_E8(kB, aB0, aB1, aB2, aB3)
        kA += 8; kB += 8;
    }
    while (kA + 8 <= reA) { G2_E8(kA, aA0, aA1, aA2, aA3) kA += 8; }
    while (kB + 8 <= reB) { G2_E8(kB, aB0, aB1, aB2, aB3) kB += 8; }
    while (kA + 4 <= reA && kB + 4 <= reB) {
        G2_E4(kA, aA0, aA1, aA2, aA3)
        G2_E4(kB, aB0, aB1, aB2, aB3)
        kA += 4; kB += 4;
    }
    while (kA + 4 <= reA) { G2_E4(kA, aA0, aA1, aA2, aA3) kA += 4; }
    while (kB + 4 <= reB) { G2_E4(kB, aB0, aB1, aB2, aB3) kB += 4; }
    while (kA < reA && kB < reB) { G2_E1(kA, aA0) G2_E1(kB, aB0) kA++; kB++; }
    while (kA < reA) { G2_E1(kA, aA0) kA++; }
    while (kB < reB) { G2_E1(kB, aB0) kB++; }
    float2 rA, rB;
    rA.x = dA * (aA0.x + aA1.x + aA2.x + aA3.x + bflo(usA));
    rA.y = dA * (aA0.y + aA1.y + aA2.y + aA3.y + bfhi(usA));
    rB.x = dB * (aB0.x + aB1.x + aB2.x + aB3.x + bflo(usB));
    rB.y = dB * (aB0.y + aB1.y + aB2.y + aB3.y + bfhi(usB));
    red[w * 2][lane] = rA;
    red[w * 2 + 1][lane] = rB;
    __syncthreads();
    int g0 = batch[blockIdx.x * 16];
    int gF = batch[blockIdx.x * 16 + 15];
    if (g0 == gF) {
        if (w == 0) {
            float sx = 0.f, sy = 0.f;
#pragma unroll
            for (int q = 0; q < 16; q++) { sx += red[q][lane].x; sy += red[q][lane].y; }
            atomicAdd(&gsum2[g0 * 128 + 2 * lane], sx);
            atomicAdd(&gsum2[g0 * 128 + 2 * lane + 1], sy);
        }
    } else {
        int gA = batch[nA], gB = batch[nB];
        atomicAdd(&gsum2[gA * 128 + 2 * lane], rA.x);
        atomicAdd(&gsum2[gA * 128 + 2 * lane + 1], rA.y);
        atomicAdd(&gsum2[gB * 128 + 2 * lane], rB.x);
        atomicAdd(&gsum2[gB * 128 + 2 * lane + 1], rB.y);
    }
}

// ---------------- final: gcnt (binary search) + z = mean2 @ W2 + b2 ; MLP ----------------

__global__ __launch_bounds__(128) void k_mlp(const float* __restrict__ gsum2,
                                             const float* __restrict__ gt_sum,
                                             const int* __restrict__ batch,
                                             const float* __restrict__ W2,
                                             const float* __restrict__ b2,
                                             const float* __restrict__ Wm1,
                                             const float* __restrict__ bm1,
                                             const float* __restrict__ Wm2,
                                             const float* __restrict__ bm2,
                                             float* __restrict__ out) {
    __shared__ float srow[HIDDEN];
    __shared__ float g144[HIDDEN + GRAPH_DIM];
    __shared__ float sm[HIDDEN];
    __shared__ int cnt_sh;
    int b = blockIdx.x;
    int j = threadIdx.x;  // 0..127
    float raw = gsum2[b * 128 + j];
    float gtraw = (j < GRAPH_DIM) ? gt_sum[b * GRAPH_DIM + j] : 0.0f;
    if (j == 0) {
        int lo = 0, hi = N_NODES;
        while (lo < hi) { int m = (lo + hi) >> 1; if (batch[m] < b) lo = m + 1; else hi = m; }
        int a = lo;
        lo = 0; hi = N_NODES;
        while (lo < hi) { int m = (lo + hi) >> 1; if (batch[m] < b + 1) lo = m + 1; else hi = m; }
        cnt_sh = lo - a;
    }
    __syncthreads();
    float inv = 1.0f / fmaxf((float)cnt_sh, 1.0f);
    srow[j] = raw * inv;
    if (j < GRAPH_DIM) g144[128 + j] = gtraw * inv;
    __syncthreads();
    float z = b2[j];
    for (int k = 0; k < 128; k++) z += srow[k] * W2[k * 128 + j];
    g144[j] = z;
    __syncthreads();
    float acc = bm1[j];
    for (int k = 0; k < HIDDEN + GRAPH_DIM; k++) acc += g144[k] * Wm1[k * 128 + j];
    sm[j] = fmaxf(acc, 0.0f);
    __syncthreads();
    if (j < OUT_DIM) {
        float o = bm2[j];
        for (int k = 0; k < 128; k++) o += sm[k] * Wm2[k * OUT_DIM + j];
        out[b * OUT_DIM + j] = o;
    }
}

extern "C" void kernel_launch(void* const* d_in, const int* in_sizes, int n_in,
                              void* d_out, int out_size, void* d_ws, size_t ws_size,
                              hipStream_t stream) {
    const float* x    = (const float*)d_in[0];
    const int*   edge = (const int*)d_in[1];
    const int*   src  = edge;
    const int*   dst  = edge + N_EDGES;
    const int*   batch= (const int*)d_in[2];
    const float* W1   = (const float*)d_in[3];
    const float* b1   = (const float*)d_in[4];
    const float* W2   = (const float*)d_in[5];
    const float* b2   = (const float*)d_in[6];
    const float* Wm1  = (const float*)d_in[7];
    const float* bm1  = (const float*)d_in[8];
    const float* Wm2  = (const float*)d_in[9];
    const float* bm2  = (const float*)d_in[10];
    float* out = (float*)d_out;

    // workspace layout (~66 MB); gcur and gt_sum adjacent for one memset
    char* ws = (char*)d_ws;
    char* p = ws;
    unsigned* bin   = (unsigned*)p;  p += (size_t)NBUCKETS * BIN_CAP * 4;   // 12.8 MB
    int*   csr      = (int*)p;       p += (size_t)NBUCKETS * BIN_CAP * 4;   // 12.8 MB (bucket regions)
    ushort* h1b     = (ushort*)p;    p += (size_t)N_NODES * 128 * 2;        // 25.6 MB (hs = dinv*h1)
    ushort* xb      = (ushort*)p;    p += (size_t)N_NODES * 64 * 2;         // 12.8 MB (xs = dinv*x64)
    int2*  rowse    = (int2*)p;      p += (size_t)N_NODES * 8;              // 800 KB
    float* dinv     = (float*)p;     p += (size_t)N_NODES * 4;
    int*   gcur     = (int*)p;       p += (size_t)NBUCKETS * 4;
    float* gt_sum   = (float*)p;     p += (size_t)N_GRAPHS * GRAPH_DIM * 4;
    float* gsum2    = (float*)p;     p += (size_t)N_GRAPHS * 128 * 4;

    // zero gcur + gt_sum in one shot (adjacent)
    hipMemsetAsync(gcur, 0, (size_t)NBUCKETS * 4 + (size_t)N_GRAPHS * GRAPH_DIM * 4, stream);

    // merged: edge binning + bf16 pack + graph stats
    k_binpack<<<NB_BIN + NB_PACK, 256, 0, stream>>>(src, dst, gcur, bin, x, batch, xb, gt_sum);

    // fused count+scan+fill per bucket, then xs = dinv * xb in place
    k_build<<<NBUCKETS, 256, 0, stream>>>(gcur, bin, dinv, rowse, csr, xb);

    // conv1 fused: z1 = dinv*(sum xs) ; hs = dinv*relu(z1 @ W1 + b1) (bf16)
    k_conv1<<<N_NODES / 16, 512, 0, stream>>>(csr, rowse, dinv, xb, W1, b1, h1b, gsum2);

    // conv2 pooled: gsum2[g] += dinv[i]*(sum_e hs[src] + hs[i])
    k_gather2<<<N_NODES / 16, 512, 0, stream>>>(csr, rowse, dinv,
                                                (const unsigned*)h1b, batch, gsum2);

    // final: gcnt + z = (gsum2/cnt) @ W2 + b2 ; MLP
    k_mlp<<<N_GRAPHS, 128, 0, stream>>>(gsum2, gt_sum, batch, W2, b2, Wm1, bm1, Wm2, bm2, out);
}

// Round 17
// 220.188 us; speedup vs baseline: 1.0548x; 1.0548x over previous
//
#include <hip/hip_runtime.h>
#include <hip/hip_bf16.h>

#define N_NODES 100000
#define N_EDGES 1600000
#define N_GRAPHS 512
#define NODE_DIM 64
#define GRAPH_DIM 16
#define HIDDEN 128
#define OUT_DIM 8

#define NBUCKETS 391      // ceil(N_NODES/256)
#define BIN_CAP 8192      // per-bucket bin + csr capacity (avg 4092)
#define EPB 4096          // edges per binning block
#define NB_BIN 391        // binplace blocks = ceil(N_EDGES/EPB)
#define NB_PACK 1563      // packstat blocks = ceil(N_NODES/64)

__device__ __forceinline__ float bflo(unsigned u) { return __uint_as_float(u << 16); }
__device__ __forceinline__ float bfhi(unsigned u) { return __uint_as_float(u & 0xffff0000u); }

// ---- merged phase A: blocks [0,NB_BIN) bin edges by dst>>8; blocks [NB_BIN,..) pack x + graph stats ----

__global__ __launch_bounds__(256) void k_binpack(const int* __restrict__ src,
                                                 const int* __restrict__ dst,
                                                 int* __restrict__ gcur,
                                                 unsigned* __restrict__ bin,
                                                 const float* __restrict__ x,
                                                 const int* __restrict__ batch,
                                                 ushort* __restrict__ xb,
                                                 float* __restrict__ gt_sum) {
    int t = threadIdx.x;
    if (blockIdx.x < NB_BIN) {
        __shared__ int cnt[NBUCKETS];
        __shared__ int base[NBUCKETS];
        for (int i = t; i < NBUCKETS; i += 256) cnt[i] = 0;
        __syncthreads();
        int e0 = blockIdx.x * EPB;
#pragma unroll
        for (int k = 0; k < EPB / 256; k++) {
            int e = e0 + k * 256 + t;
            if (e < N_EDGES) atomicAdd(&cnt[dst[e] >> 8], 1);
        }
        __syncthreads();
        for (int i = t; i < NBUCKETS; i += 256) {
            int c = cnt[i];
            base[i] = (c > 0) ? atomicAdd(&gcur[i], c) : 0;
            cnt[i] = 0;
        }
        __syncthreads();
#pragma unroll
        for (int k = 0; k < EPB / 256; k++) {
            int e = e0 + k * 256 + t;
            if (e < N_EDGES) {
                int d = dst[e];
                int b = d >> 8;
                int p = atomicAdd(&cnt[b], 1);
                bin[(size_t)b * BIN_CAP + base[b] + p] = ((unsigned)src[e] << 8) | (unsigned)(d & 255);
            }
        }
    } else {
        int i0 = (blockIdx.x - NB_BIN) * 64;
        for (int idx = t; idx < 64 * 32; idx += 256) {
            int node = i0 + (idx >> 5);
            if (node < N_NODES) {
                int c2 = idx & 31;
                float2 v = *(const float2*)&x[(size_t)node * 80 + c2 * 2];
                __hip_bfloat16 lo = __float2bfloat16(v.x);
                __hip_bfloat16 hi = __float2bfloat16(v.y);
                ushort2 pv = make_ushort2(*(ushort*)&lo, *(ushort*)&hi);
                ((ushort2*)xb)[(size_t)node * 32 + c2] = pv;
            }
        }
        int c = t & 15, sub = t >> 4;  // 16 subs x 16 channels
        int iend = min(i0 + 64, N_NODES);
        float acc = 0.0f;
        int g = -1;
        for (int i = i0 + sub; i < iend; i += 16) {
            int bi = batch[i];
            if (bi != g) {
                if (g >= 0) atomicAdd(&gt_sum[g * GRAPH_DIM + c], acc);
                acc = 0.0f; g = bi;
            }
            acc += x[(size_t)i * 80 + NODE_DIM + c];
        }
        if (g >= 0) atomicAdd(&gt_sum[g * GRAPH_DIM + c], acc);
    }
}

// ---- phase B (fused): count -> dinv + rowse -> CSR fill -> in-place rescale xb *= dinv ----

__global__ __launch_bounds__(256) void k_build(const int* __restrict__ gcur,
                                               const unsigned* __restrict__ bin,
                                               float* __restrict__ dinv,
                                               int2* __restrict__ rowse,
                                               int* __restrict__ csr,
                                               ushort* __restrict__ xb) {
    __shared__ int cnt[256];
    __shared__ int sc[256];
    __shared__ int rsl[256];
    __shared__ float dl[256];
    int b = blockIdx.x, t = threadIdx.x;
    cnt[t] = 0;
    __syncthreads();
    int n = gcur[b];
    const unsigned* seg = bin + (size_t)b * BIN_CAP;
    for (int i = t; i < n; i += 256) atomicAdd(&cnt[seg[i] & 255u], 1);
    __syncthreads();
    int deg = cnt[t];
    sc[t] = deg;
    __syncthreads();
    for (int o = 1; o < 256; o <<= 1) {
        int u = (t >= o) ? sc[t - o] : 0;
        __syncthreads();
        sc[t] += u;
        __syncthreads();
    }
    int rs = b * BIN_CAP + sc[t] - deg;   // bucket-region base, exclusive prefix
    int node = b * 256 + t;
    float dv = rsqrtf((float)deg + 1.0f);
    if (node < N_NODES) {
        dinv[node] = dv;
        rowse[node] = make_int2(rs, rs + deg);
    }
    rsl[t] = rs;
    dl[t] = dv;
    cnt[t] = 0;
    __syncthreads();
    for (int i = t; i < n; i += 256) {
        unsigned e = seg[i];
        int dlidx = (int)(e & 255u);
        csr[rsl[dlidx] + atomicAdd(&cnt[dlidx], 1)] = (int)(e >> 8);
    }
    __syncthreads();
    // in-place rescale: xs = bf16(dinv * xb)
    unsigned* xw = (unsigned*)xb;
    for (int idx = t; idx < 256 * 32; idx += 256) {
        int nl = idx >> 5;
        int nn = b * 256 + nl;
        if (nn < N_NODES) {
            int c2 = idx & 31;
            unsigned u = xw[(size_t)nn * 32 + c2];
            float d = dl[nl];
            float lo = bflo(u) * d;
            float hi = bfhi(u) * d;
            __hip_bfloat16 l2 = __float2bfloat16(lo);
            __hip_bfloat16 h2 = __float2bfloat16(hi);
            xw[(size_t)nn * 32 + c2] = ((unsigned)(*(ushort*)&h2) << 16) | (unsigned)(*(ushort*)&l2);
        }
    }
}

// ---- fused conv1: weightless unroll-8 cascade gather + full-block GEMM; zeroes gsum2 ----
// z[i] = dinv[i] * (sum_e xs[src_e] + xs[i]);  h_s = bf16(dinv * relu(z @ W1 + b1))

#define LDX(s_) __uint_as_float((unsigned)xb[(size_t)(s_)*64 + lane] << 16)

#define C1_E8(kX, aX0, aX1, aX2, aX3) {                                              \
    int s0 = csr[kX],     s1 = csr[kX + 1], s2 = csr[kX + 2], s3 = csr[kX + 3];      \
    int s4 = csr[kX + 4], s5 = csr[kX + 5], s6 = csr[kX + 6], s7 = csr[kX + 7];      \
    float v0 = LDX(s0), v1 = LDX(s1), v2 = LDX(s2), v3 = LDX(s3);                    \
    float v4 = LDX(s4), v5 = LDX(s5), v6 = LDX(s6), v7 = LDX(s7);                    \
    aX0 += v0; aX1 += v1; aX2 += v2; aX3 += v3;                                      \
    aX0 += v4; aX1 += v5; aX2 += v6; aX3 += v7; }

#define C1_E4(kX, aX0, aX1, aX2, aX3) {                                              \
    int s0 = csr[kX], s1 = csr[kX + 1], s2 = csr[kX + 2], s3 = csr[kX + 3];          \
    float v0 = LDX(s0), v1 = LDX(s1), v2 = LDX(s2), v3 = LDX(s3);                    \
    aX0 += v0; aX1 += v1; aX2 += v2; aX3 += v3; }

#define C1_E1(kX, aX0) { int s0 = csr[kX]; aX0 += LDX(s0); }

__global__ __launch_bounds__(256) void k_conv1(const int* __restrict__ csr,
                                               const int2* __restrict__ rowse,
                                               const float* __restrict__ dinv,
                                               const ushort* __restrict__ xb,
                                               const float* __restrict__ W,
                                               const float* __restrict__ bias,
                                               ushort* __restrict__ C,
                                               float* __restrict__ gsum2) {
    __shared__ float zs[8][64];
    int t = threadIdx.x;
    if (blockIdx.x < 256) gsum2[blockIdx.x * 256 + t] = 0.0f;
    int w = t >> 6, lane = t & 63;
    int nA = blockIdx.x * 8 + w * 2;
    int nB = nA + 1;
    int2 seA = rowse[nA];
    int2 seB = rowse[nB];
    int kA = seA.x, reA = seA.y;
    int kB = seB.x, reB = seB.y;
    float dA = dinv[nA], dB = dinv[nB];
    float aA0 = 0.f, aA1 = 0.f, aA2 = 0.f, aA3 = 0.f;
    float aB0 = 0.f, aB1 = 0.f, aB2 = 0.f, aB3 = 0.f;
    while (kA + 8 <= reA && kB + 8 <= reB) {
        C1_E8(kA, aA0, aA1, aA2, aA3)
        C1_E8(kB, aB0, aB1, aB2, aB3)
        kA += 8; kB += 8;
    }
    while (kA + 8 <= reA) { C1_E8(kA, aA0, aA1, aA2, aA3) kA += 8; }
    while (kB + 8 <= reB) { C1_E8(kB, aB0, aB1, aB2, aB3) kB += 8; }
    while (kA + 4 <= reA && kB + 4 <= reB) {
        C1_E4(kA, aA0, aA1, aA2, aA3)
        C1_E4(kB, aB0, aB1, aB2, aB3)
        kA += 4; kB += 4;
    }
    while (kA + 4 <= reA) { C1_E4(kA, aA0, aA1, aA2, aA3) kA += 4; }
    while (kB + 4 <= reB) { C1_E4(kB, aB0, aB1, aB2, aB3) kB += 4; }
    while (kA < reA && kB < reB) { C1_E1(kA, aA0) C1_E1(kB, aB0) kA++; kB++; }
    while (kA < reA) { C1_E1(kA, aA0) kA++; }
    while (kB < reB) { C1_E1(kB, aB0) kB++; }
    zs[w * 2][lane]     = dA * (aA0 + aA1 + aA2 + aA3 + LDX(nA));
    zs[w * 2 + 1][lane] = dB * (aB0 + aB1 + aB2 + aB3 + LDX(nB));
    __syncthreads();
    // GEMM phase: all 256 threads; j = t&127, half hf computes rows hf*4 .. hf*4+3
    {
        int j = t & 127;
        int hf = t >> 7;
        float acc[4];
#pragma unroll
        for (int m = 0; m < 4; m++) acc[m] = 0.0f;
        for (int k = 0; k < 64; k++) {
            float wk = W[k * 128 + j];
#pragma unroll
            for (int m = 0; m < 4; m++) acc[m] += zs[hf * 4 + m][k] * wk;
        }
        float b = bias[j];
        size_t row0 = (size_t)blockIdx.x * 8 + hf * 4;
#pragma unroll
        for (int m = 0; m < 4; m++) {
            float v = fmaxf(acc[m] + b, 0.0f) * dinv[row0 + m];
            __hip_bfloat16 hv = __float2bfloat16(v);
            C[(row0 + m) * 128 + j] = *(ushort*)&hv;
        }
    }
}

// ---- gather2: weightless unroll-8 cascade (hs bf16, 2 nodes/wave, 2ch/lane) + fused mean-pool ----
// pool-row[i] = dinv[i] * (sum_e hs[src_e] + hs[i])

#define ADD2(acc_, u_) { acc_.x += bflo(u_); acc_.y += bfhi(u_); }

#define G2_E8(kX, aX0, aX1, aX2, aX3) {                                              \
    int s0 = csr[kX],     s1 = csr[kX + 1], s2 = csr[kX + 2], s3 = csr[kX + 3];      \
    int s4 = csr[kX + 4], s5 = csr[kX + 5], s6 = csr[kX + 6], s7 = csr[kX + 7];      \
    unsigned u0 = h[(size_t)s0 * 64 + lane], u1 = h[(size_t)s1 * 64 + lane];         \
    unsigned u2 = h[(size_t)s2 * 64 + lane], u3 = h[(size_t)s3 * 64 + lane];         \
    unsigned u4 = h[(size_t)s4 * 64 + lane], u5 = h[(size_t)s5 * 64 + lane];         \
    unsigned u6 = h[(size_t)s6 * 64 + lane], u7 = h[(size_t)s7 * 64 + lane];         \
    ADD2(aX0, u0) ADD2(aX1, u1) ADD2(aX2, u2) ADD2(aX3, u3)                          \
    ADD2(aX0, u4) ADD2(aX1, u5) ADD2(aX2, u6) ADD2(aX3, u7) }

#define G2_E4(kX, aX0, aX1, aX2, aX3) {                                              \
    int s0 = csr[kX], s1 = csr[kX + 1], s2 = csr[kX + 2], s3 = csr[kX + 3];          \
    unsigned u0 = h[(size_t)s0 * 64 + lane], u1 = h[(size_t)s1 * 64 + lane];         \
    unsigned u2 = h[(size_t)s2 * 64 + lane], u3 = h[(size_t)s3 * 64 + lane];         \
    ADD2(aX0, u0) ADD2(aX1, u1) ADD2(aX2, u2) ADD2(aX3, u3) }

#define G2_E1(kX, aX0) {                                                             \
    int s0 = csr[kX];                                                                \
    unsigned u0 = h[(size_t)s0 * 64 + lane];                                         \
    ADD2(aX0, u0) }

__global__ __launch_bounds__(256) void k_gather2(const int* __restrict__ csr,
                                                 const int2* __restrict__ rowse,
                                                 const float* __restrict__ dinv,
                                                 const unsigned* __restrict__ h,
                                                 const int* __restrict__ batch,
                                                 float* __restrict__ gsum2) {
    __shared__ float2 red[8][64];
    int w = threadIdx.x >> 6, lane = threadIdx.x & 63;
    int nA = blockIdx.x * 8 + w * 2;
    int nB = nA + 1;
    int2 seA = rowse[nA];
    int2 seB = rowse[nB];
    int kA = seA.x, reA = seA.y;
    int kB = seB.x, reB = seB.y;
    float dA = dinv[nA], dB = dinv[nB];
    float2 aA0 = {0.f,0.f}, aA1 = {0.f,0.f}, aA2 = {0.f,0.f}, aA3 = {0.f,0.f};
    float2 aB0 = {0.f,0.f}, aB1 = {0.f,0.f}, aB2 = {0.f,0.f}, aB3 = {0.f,0.f};
    while (kA + 8 <= reA && kB + 8 <= reB) {
        G2_E8(kA, aA0, aA1, aA2, aA3)
        G2_E8(kB, aB0, aB1, aB2, aB3)
        kA += 8; kB += 8;
    }
    while (kA + 8 <= reA) { G2_E8(kA, aA0, aA1, aA2, aA3) kA += 8; }
    while (kB + 8 <= reB) { G2_E8(kB, aB0, aB1, aB2, aB3) kB += 8; }
    while (kA + 4 <= reA && kB + 4 <= reB) {
        G2_E4(kA, aA0, aA1, aA2, aA3)
        G2_E4(kB, aB0, aB1, aB2, aB3)
        kA += 4; kB += 4;
    }
    while (kA + 4 <= reA) { G2_E4(kA, aA0, aA1, aA2, aA3) kA += 4; }
    while (kB + 4 <= reB) { G2_E4(kB, aB0, aB1, aB2, aB3) kB += 4; }
    while (kA < reA && kB < reB) { G2_E1(kA, aA0) G2_E1(kB, aB0) kA++; kB++; }
    while (kA < reA) { G2_E1(kA, aA0) kA++; }
    while (kB < reB) { G2_E1(kB, aB0) kB++; }
    unsigned usA = h[(size_t)nA * 64 + lane];
    unsigned usB = h[(size_t)nB * 64 + lane];
    float2 rA, rB;
    rA.x = dA * (aA0.x + aA1.x + aA2.x + aA3.x + bflo(usA));
    rA.y = dA * (aA0.y + aA1.y + aA2.y + aA3.y + bfhi(usA));
    rB.x = dB * (aB0.x + aB1.x + aB2.x + aB3.x + bflo(usB));
    rB.y = dB * (aB0.y + aB1.y + aB2.y + aB3.y + bfhi(usB));
    red[w * 2][lane] = rA;
    red[w * 2 + 1][lane] = rB;
    __syncthreads();
    int g0 = batch[blockIdx.x * 8];
    int g7 = batch[blockIdx.x * 8 + 7];
    if (g0 == g7) {
        if (w == 0) {
            float sx = 0.f, sy = 0.f;
#pragma unroll
            for (int q = 0; q < 8; q++) { sx += red[q][lane].x; sy += red[q][lane].y; }
            atomicAdd(&gsum2[g0 * 128 + 2 * lane], sx);
            atomicAdd(&gsum2[g0 * 128 + 2 * lane + 1], sy);
        }
    } else {
        int gA = batch[nA], gB = batch[nB];
        atomicAdd(&gsum2[gA * 128 + 2 * lane], rA.x);
        atomicAdd(&gsum2[gA * 128 + 2 * lane + 1], rA.y);
        atomicAdd(&gsum2[gB * 128 + 2 * lane], rB.x);
        atomicAdd(&gsum2[gB * 128 + 2 * lane + 1], rB.y);
    }
}

// ---------------- final: gcnt (binary search) + z = mean2 @ W2 + b2 ; MLP ----------------

__global__ __launch_bounds__(128) void k_mlp(const float* __restrict__ gsum2,
                                             const float* __restrict__ gt_sum,
                                             const int* __restrict__ batch,
                                             const float* __restrict__ W2,
                                             const float* __restrict__ b2,
                                             const float* __restrict__ Wm1,
                                             const float* __restrict__ bm1,
                                             const float* __restrict__ Wm2,
                                             const float* __restrict__ bm2,
                                             float* __restrict__ out) {
    __shared__ float srow[HIDDEN];
    __shared__ float g144[HIDDEN + GRAPH_DIM];
    __shared__ float sm[HIDDEN];
    __shared__ int cnt_sh;
    int b = blockIdx.x;
    int j = threadIdx.x;  // 0..127
    float raw = gsum2[b * 128 + j];
    float gtraw = (j < GRAPH_DIM) ? gt_sum[b * GRAPH_DIM + j] : 0.0f;
    if (j == 0) {
        int lo = 0, hi = N_NODES;
        while (lo < hi) { int m = (lo + hi) >> 1; if (batch[m] < b) lo = m + 1; else hi = m; }
        int a = lo;
        lo = 0; hi = N_NODES;
        while (lo < hi) { int m = (lo + hi) >> 1; if (batch[m] < b + 1) lo = m + 1; else hi = m; }
        cnt_sh = lo - a;
    }
    __syncthreads();
    float inv = 1.0f / fmaxf((float)cnt_sh, 1.0f);
    srow[j] = raw * inv;
    if (j < GRAPH_DIM) g144[128 + j] = gtraw * inv;
    __syncthreads();
    float z = b2[j];
    for (int k = 0; k < 128; k++) z += srow[k] * W2[k * 128 + j];
    g144[j] = z;
    __syncthreads();
    float acc = bm1[j];
    for (int k = 0; k < HIDDEN + GRAPH_DIM; k++) acc += g144[k] * Wm1[k * 128 + j];
    sm[j] = fmaxf(acc, 0.0f);
    __syncthreads();
    if (j < OUT_DIM) {
        float o = bm2[j];
        for (int k = 0; k < 128; k++) o += sm[k] * Wm2[k * OUT_DIM + j];
        out[b * OUT_DIM + j] = o;
    }
}

extern "C" void kernel_launch(void* const* d_in, const int* in_sizes, int n_in,
                              void* d_out, int out_size, void* d_ws, size_t ws_size,
                              hipStream_t stream) {
    const float* x    = (const float*)d_in[0];
    const int*   edge = (const int*)d_in[1];
    const int*   src  = edge;
    const int*   dst  = edge + N_EDGES;
    const int*   batch= (const int*)d_in[2];
    const float* W1   = (const float*)d_in[3];
    const float* b1   = (const float*)d_in[4];
    const float* W2   = (const float*)d_in[5];
    const float* b2   = (const float*)d_in[6];
    const float* Wm1  = (const float*)d_in[7];
    const float* bm1  = (const float*)d_in[8];
    const float* Wm2  = (const float*)d_in[9];
    const float* bm2  = (const float*)d_in[10];
    float* out = (float*)d_out;

    // workspace layout (~66 MB); gcur and gt_sum adjacent for one memset
    char* ws = (char*)d_ws;
    char* p = ws;
    unsigned* bin   = (unsigned*)p;  p += (size_t)NBUCKETS * BIN_CAP * 4;   // 12.8 MB
    int*   csr      = (int*)p;       p += (size_t)NBUCKETS * BIN_CAP * 4;   // 12.8 MB (bucket regions)
    ushort* h1b     = (ushort*)p;    p += (size_t)N_NODES * 128 * 2;        // 25.6 MB (hs = dinv*h1)
    ushort* xb      = (ushort*)p;    p += (size_t)N_NODES * 64 * 2;         // 12.8 MB (xs = dinv*x64)
    int2*  rowse    = (int2*)p;      p += (size_t)N_NODES * 8;              // 800 KB
    float* dinv     = (float*)p;     p += (size_t)N_NODES * 4;
    int*   gcur     = (int*)p;       p += (size_t)NBUCKETS * 4;
    float* gt_sum   = (float*)p;     p += (size_t)N_GRAPHS * GRAPH_DIM * 4;
    float* gsum2    = (float*)p;     p += (size_t)N_GRAPHS * 128 * 4;

    // zero gcur + gt_sum in one shot (adjacent)
    hipMemsetAsync(gcur, 0, (size_t)NBUCKETS * 4 + (size_t)N_GRAPHS * GRAPH_DIM * 4, stream);

    // merged: edge binning + bf16 pack + graph stats
    k_binpack<<<NB_BIN + NB_PACK, 256, 0, stream>>>(src, dst, gcur, bin, x, batch, xb, gt_sum);

    // fused count+scan+fill per bucket, then xs = dinv * xb in place
    k_build<<<NBUCKETS, 256, 0, stream>>>(gcur, bin, dinv, rowse, csr, xb);

    // conv1 fused: z1 = dinv*(sum xs) ; hs = dinv*relu(z1 @ W1 + b1) (bf16)
    k_conv1<<<N_NODES / 8, 256, 0, stream>>>(csr, rowse, dinv, xb, W1, b1, h1b, gsum2);

    // conv2 pooled: gsum2[g] += dinv[i]*(sum_e hs[src] + hs[i])
    k_gather2<<<N_NODES / 8, 256, 0, stream>>>(csr, rowse, dinv,
                                               (const unsigned*)h1b, batch, gsum2);

    // final: gcnt + z = (gsum2/cnt) @ W2 + b2 ; MLP
    k_mlp<<<N_GRAPHS, 128, 0, stream>>>(gsum2, gt_sum, batch, W2, b2, Wm1, bm1, Wm2, bm2, out);
}